// Round 1
// baseline (497.357 us; speedup 1.0000x reference)
//
#include <hip/hip_runtime.h>

#define N_NODES 50000
#define N_EDGES 800000
#define D 128
#define NGRAPH 50

// ---------------- setup: degree, norm, CSR ----------------
__global__ void k_deg(const int* __restrict__ dst, int* __restrict__ deg) {
  int e = blockIdx.x * 256 + threadIdx.x;
  if (e < N_EDGES) atomicAdd(&deg[dst[e]], 1);
}

__global__ void k_dinv(const int* __restrict__ deg, float* __restrict__ dinv) {
  int i = blockIdx.x * 256 + threadIdx.x;
  if (i < N_NODES) dinv[i] = rsqrtf((float)deg[i] + 1.0f);  // +1 self loop
}

__global__ void k_scan1(const int* __restrict__ deg, int* __restrict__ offs,
                        int* __restrict__ bsum) {
  __shared__ int s[256];
  int t = threadIdx.x;
  int i = blockIdx.x * 256 + t;
  int v = (i < N_NODES) ? deg[i] : 0;
  s[t] = v;
  __syncthreads();
  for (int off = 1; off < 256; off <<= 1) {
    int tmp = (t >= off) ? s[t - off] : 0;
    __syncthreads();
    s[t] += tmp;
    __syncthreads();
  }
  if (i < N_NODES) offs[i] = s[t] - v;   // exclusive within block
  if (t == 255) bsum[blockIdx.x] = s[t]; // block total
}

__global__ void k_scan2(const int* __restrict__ bsum, int* __restrict__ bbase, int nb) {
  __shared__ int s[256];
  int t = threadIdx.x;
  int v = (t < nb) ? bsum[t] : 0;
  s[t] = v;
  __syncthreads();
  for (int off = 1; off < 256; off <<= 1) {
    int tmp = (t >= off) ? s[t - off] : 0;
    __syncthreads();
    s[t] += tmp;
    __syncthreads();
  }
  bbase[t] = s[t] - v;
}

__global__ void k_scan3(int* __restrict__ offs, const int* __restrict__ bbase) {
  int i = blockIdx.x * 256 + threadIdx.x;
  if (i < N_NODES) offs[i] += bbase[blockIdx.x];
  if (i == 0) offs[N_NODES] = N_EDGES;
}

__global__ void k_fill(const int* __restrict__ src, const int* __restrict__ dst,
                       const int* __restrict__ offs, int* __restrict__ cursor,
                       int* __restrict__ csr) {
  int e = blockIdx.x * 256 + threadIdx.x;
  if (e < N_EDGES) {
    int d = dst[e];
    int pos = offs[d] + atomicAdd(&cursor[d], 1);
    csr[pos] = src[e];
  }
}

// ---------------- GEMM: G = rowscale(A @ W, dinv) ----------------
// A: [N_NODES,128] f32, W: [128,128] f32. 64x64 tile, 256 threads, 4x4/thread.
__global__ __launch_bounds__(256) void k_gemm(const float* __restrict__ A,
                                              const float* __restrict__ W,
                                              const float* __restrict__ dinv,
                                              float* __restrict__ G) {
  __shared__ float As[64][132];  // +4 pad -> rg groups land 2-way (free)
  __shared__ float Bs[128][64];
  int r0 = blockIdx.x * 64;
  int c0 = blockIdx.y * 64;
  int t = threadIdx.x;

  // stage A tile (64x128)
  for (int i = t; i < 2048; i += 256) {
    int row = i >> 5, c4 = i & 31;
    int gr = r0 + row;
    float4 v = make_float4(0.f, 0.f, 0.f, 0.f);
    if (gr < N_NODES) v = reinterpret_cast<const float4*>(A)[gr * 32 + c4];
    *reinterpret_cast<float4*>(&As[row][c4 * 4]) = v;
  }
  // stage B half (128x64)
  for (int i = t; i < 2048; i += 256) {
    int row = i >> 4, c4 = i & 15;
    *reinterpret_cast<float4*>(&Bs[row][c4 * 4]) =
        reinterpret_cast<const float4*>(W)[row * 32 + (c0 >> 2) + c4];
  }
  __syncthreads();

  int cg = t & 15, rg = t >> 4;
  float acc[4][4] = {};
  for (int k = 0; k < 128; k += 4) {
    float4 b[4];
#pragma unroll
    for (int kk = 0; kk < 4; ++kk)
      b[kk] = *reinterpret_cast<const float4*>(&Bs[k + kk][cg * 4]);
#pragma unroll
    for (int i = 0; i < 4; ++i) {
      float4 a = *reinterpret_cast<const float4*>(&As[rg * 4 + i][k]);
      float av[4] = {a.x, a.y, a.z, a.w};
#pragma unroll
      for (int kk = 0; kk < 4; ++kk) {
        acc[i][0] = fmaf(av[kk], b[kk].x, acc[i][0]);
        acc[i][1] = fmaf(av[kk], b[kk].y, acc[i][1]);
        acc[i][2] = fmaf(av[kk], b[kk].z, acc[i][2]);
        acc[i][3] = fmaf(av[kk], b[kk].w, acc[i][3]);
      }
    }
  }
#pragma unroll
  for (int i = 0; i < 4; ++i) {
    int r = r0 + rg * 4 + i;
    if (r < N_NODES) {
      float d = dinv[r];
      float4 o = make_float4(d * acc[i][0], d * acc[i][1], d * acc[i][2], d * acc[i][3]);
      reinterpret_cast<float4*>(G)[r * 32 + (c0 >> 2) + cg] = o;
    }
  }
}

// ---------------- aggregation: wave per node ----------------
__global__ __launch_bounds__(256) void k_agg(const float* __restrict__ g,
                                             const int* __restrict__ offs,
                                             const int* __restrict__ csr,
                                             const float* __restrict__ dinv,
                                             const float* __restrict__ bc,
                                             float* __restrict__ xo) {
  int w = threadIdx.x >> 6;
  int i = blockIdx.x * 4 + w;
  if (i >= N_NODES) return;
  int l = threadIdx.x & 63;
  const float2* g2 = reinterpret_cast<const float2*>(g);
  float2 acc = g2[(size_t)i * 64 + l];  // self loop term
  int e0 = offs[i], e1 = offs[i + 1];
  for (int e = e0; e < e1; ++e) {
    int s = csr[e];
    float2 v = g2[(size_t)s * 64 + l];
    acc.x += v.x;
    acc.y += v.y;
  }
  float di = dinv[i];
  const float2* b2 = reinterpret_cast<const float2*>(bc);
  float2 bb = b2[l];
  float2 o;
  o.x = fmaxf(fmaf(di, acc.x, bb.x), 0.f);
  o.y = fmaxf(fmaf(di, acc.y, bb.y), 0.f);
  reinterpret_cast<float2*>(xo)[(size_t)i * 64 + l] = o;
}

// ---------------- pooling ----------------
__global__ void k_gbounds(const int* __restrict__ batch, int* __restrict__ gstart) {
  int g = threadIdx.x;
  if (g > NGRAPH) return;
  int lo = 0, hi = N_NODES;
  while (lo < hi) {
    int mid = (lo + hi) >> 1;
    if (batch[mid] < g) lo = mid + 1; else hi = mid;
  }
  gstart[g] = lo;
}

__global__ __launch_bounds__(256) void k_pool(const float* __restrict__ x,
                                              const int* __restrict__ gstart,
                                              float* __restrict__ pool) {
  int g = blockIdx.x, ch = blockIdx.y;  // 8 chunks per graph
  int s = gstart[g], e = gstart[g + 1];
  long len = e - s;
  int cs = s + (int)(len * ch / 8);
  int ce = s + (int)(len * (ch + 1) / 8);
  int sub = threadIdx.x >> 6, l = threadIdx.x & 63;
  const float2* x2 = reinterpret_cast<const float2*>(x);
  float2 acc = make_float2(0.f, 0.f);
  for (int n = cs + sub; n < ce; n += 4) {
    float2 v = x2[(size_t)n * 64 + l];
    acc.x += v.x;
    acc.y += v.y;
  }
  atomicAdd(&pool[g * D + 2 * l], acc.x);
  atomicAdd(&pool[g * D + 2 * l + 1], acc.y);
}

// ---------------- MLP head ----------------
__global__ __launch_bounds__(128) void k_fc(const float* __restrict__ pool,
                                            const float* __restrict__ Wf,
                                            const float* __restrict__ bf,
                                            float* __restrict__ out) {
  __shared__ float row[D];
  int g = blockIdx.x, c = threadIdx.x;
  row[c] = pool[g * D + c];
  __syncthreads();
  for (int l = 0; l < 3; ++l) {
    const float* W = Wf + l * D * D;
    float s = bf[l * D + c];
    for (int k = 0; k < D; ++k) s = fmaf(row[k], W[k * D + c], s);
    s = fmaxf(s, 0.f);
    __syncthreads();
    row[c] = s;
    __syncthreads();
  }
  out[g * D + c] = row[c];
}

extern "C" void kernel_launch(void* const* d_in, const int* in_sizes, int n_in,
                              void* d_out, int out_size, void* d_ws, size_t ws_size,
                              hipStream_t stream) {
  const float* x   = (const float*)d_in[0];
  const int*   ei  = (const int*)d_in[1];
  const int* batch = (const int*)d_in[2];
  const float* Wc  = (const float*)d_in[3];
  const float* bc  = (const float*)d_in[4];
  const float* Wf  = (const float*)d_in[5];
  const float* bf  = (const float*)d_in[6];
  float* out = (float*)d_out;
  const int* src = ei;
  const int* dst = ei + N_EDGES;

  char* ws = (char*)d_ws;
  size_t o = 0;
  auto take = [&](size_t b) -> void* {
    void* p = ws + o;
    o = (o + b + 255) & ~(size_t)255;
    return p;
  };
  int*   deg    = (int*)  take(N_NODES * 4);
  float* dinv   = (float*)take(N_NODES * 4);
  int*   offs   = (int*)  take((N_NODES + 1) * 4);
  int*   bsum   = (int*)  take(256 * 4);
  int*   bbase  = (int*)  take(256 * 4);
  int*   cursor = (int*)  take(N_NODES * 4);
  int*   csr    = (int*)  take(N_EDGES * 4);
  int*   gstart = (int*)  take(64 * 4);
  float* gbuf   = (float*)take((size_t)N_NODES * D * 4);
  float* xbuf   = (float*)take((size_t)N_NODES * D * 4);
  float* pool   = (float*)take(NGRAPH * D * 4);
  (void)ws_size; (void)in_sizes; (void)n_in; (void)out_size;

  hipMemsetAsync(deg, 0, N_NODES * 4, stream);
  hipMemsetAsync(cursor, 0, N_NODES * 4, stream);
  hipMemsetAsync(pool, 0, NGRAPH * D * 4, stream);

  const int NB = (N_NODES + 255) / 256;  // 196
  k_deg<<<(N_EDGES + 255) / 256, 256, 0, stream>>>(dst, deg);
  k_dinv<<<NB, 256, 0, stream>>>(deg, dinv);
  k_scan1<<<NB, 256, 0, stream>>>(deg, offs, bsum);
  k_scan2<<<1, 256, 0, stream>>>(bsum, bbase, NB);
  k_scan3<<<NB, 256, 0, stream>>>(offs, bbase);
  k_fill<<<(N_EDGES + 255) / 256, 256, 0, stream>>>(src, dst, offs, cursor, csr);

  const float* xin = x;
  for (int l = 0; l < 3; ++l) {
    k_gemm<<<dim3((N_NODES + 63) / 64, 2), 256, 0, stream>>>(xin, Wc + l * D * D, dinv, gbuf);
    k_agg<<<(N_NODES + 3) / 4, 256, 0, stream>>>(gbuf, offs, csr, dinv, bc + l * D, xbuf);
    xin = xbuf;
  }
  k_gbounds<<<1, 64, 0, stream>>>(batch, gstart);
  k_pool<<<dim3(NGRAPH, 8), 256, 0, stream>>>(xbuf, gstart, pool);
  k_fc<<<NGRAPH, 128, 0, stream>>>(pool, Wf, bf, out);
}

// Round 2
// 334.071 us; speedup vs baseline: 1.4888x; 1.4888x over previous
//
#include <hip/hip_runtime.h>

#define N_NODES 50000
#define N_EDGES 800000
#define D 128
#define NGRAPH 50

typedef unsigned int uint32;
typedef unsigned short ushort16;

__device__ inline float bf_lo(uint32 u) { union { uint32 u; float f; } c; c.u = u << 16; return c.f; }
__device__ inline float bf_hi(uint32 u) { union { uint32 u; float f; } c; c.u = u & 0xffff0000u; return c.f; }
__device__ inline ushort16 f2bf(float f) {  // RNE
  union { float f; uint32 u; } c; c.f = f;
  uint32 r = (c.u + 0x7fffu + ((c.u >> 16) & 1u)) >> 16;
  return (ushort16)r;
}

// ---------------- setup: degree, norm, CSR ----------------
__global__ void k_deg(const int* __restrict__ dst, int* __restrict__ deg) {
  int e = blockIdx.x * 256 + threadIdx.x;
  if (e < N_EDGES) atomicAdd(&deg[dst[e]], 1);
}

__global__ void k_dinv(const int* __restrict__ deg, float* __restrict__ dinv) {
  int i = blockIdx.x * 256 + threadIdx.x;
  if (i < N_NODES) dinv[i] = rsqrtf((float)deg[i] + 1.0f);  // +1 self loop
}

__global__ void k_scan1(const int* __restrict__ deg, int* __restrict__ offs,
                        int* __restrict__ bsum) {
  __shared__ int s[256];
  int t = threadIdx.x;
  int i = blockIdx.x * 256 + t;
  int v = (i < N_NODES) ? deg[i] : 0;
  s[t] = v;
  __syncthreads();
  for (int off = 1; off < 256; off <<= 1) {
    int tmp = (t >= off) ? s[t - off] : 0;
    __syncthreads();
    s[t] += tmp;
    __syncthreads();
  }
  if (i < N_NODES) offs[i] = s[t] - v;
  if (t == 255) bsum[blockIdx.x] = s[t];
}

__global__ void k_scan2(const int* __restrict__ bsum, int* __restrict__ bbase, int nb) {
  __shared__ int s[256];
  int t = threadIdx.x;
  int v = (t < nb) ? bsum[t] : 0;
  s[t] = v;
  __syncthreads();
  for (int off = 1; off < 256; off <<= 1) {
    int tmp = (t >= off) ? s[t - off] : 0;
    __syncthreads();
    s[t] += tmp;
    __syncthreads();
  }
  bbase[t] = s[t] - v;
}

__global__ void k_scan3(int* __restrict__ offs, const int* __restrict__ bbase) {
  int i = blockIdx.x * 256 + threadIdx.x;
  if (i < N_NODES) offs[i] += bbase[blockIdx.x];
  if (i == 0) offs[N_NODES] = N_EDGES;
}

__global__ void k_fill(const int* __restrict__ src, const int* __restrict__ dst,
                       const int* __restrict__ offs, int* __restrict__ cursor,
                       int* __restrict__ csr) {
  int e = blockIdx.x * 256 + threadIdx.x;
  if (e < N_EDGES) {
    int d = dst[e];
    int pos = offs[d] + atomicAdd(&cursor[d], 1);
    csr[pos] = src[e];
  }
}

// ---------------- GEMM: G = rowscale(A @ W, dinv), bf16 out ----------------
__global__ __launch_bounds__(256) void k_gemm(const float* __restrict__ A,
                                              const float* __restrict__ W,
                                              const float* __restrict__ dinv,
                                              ushort16* __restrict__ G) {
  __shared__ float As[64][132];
  __shared__ float Bs[128][64];
  int r0 = blockIdx.x * 64;
  int c0 = blockIdx.y * 64;
  int t = threadIdx.x;

  for (int i = t; i < 2048; i += 256) {
    int row = i >> 5, c4 = i & 31;
    int gr = r0 + row;
    float4 v = make_float4(0.f, 0.f, 0.f, 0.f);
    if (gr < N_NODES) v = reinterpret_cast<const float4*>(A)[gr * 32 + c4];
    *reinterpret_cast<float4*>(&As[row][c4 * 4]) = v;
  }
  for (int i = t; i < 2048; i += 256) {
    int row = i >> 4, c4 = i & 15;
    *reinterpret_cast<float4*>(&Bs[row][c4 * 4]) =
        reinterpret_cast<const float4*>(W)[row * 32 + (c0 >> 2) + c4];
  }
  __syncthreads();

  int cg = t & 15, rg = t >> 4;
  float acc[4][4] = {};
  for (int k = 0; k < 128; k += 4) {
    float4 b[4];
#pragma unroll
    for (int kk = 0; kk < 4; ++kk)
      b[kk] = *reinterpret_cast<const float4*>(&Bs[k + kk][cg * 4]);
#pragma unroll
    for (int i = 0; i < 4; ++i) {
      float4 a = *reinterpret_cast<const float4*>(&As[rg * 4 + i][k]);
      float av[4] = {a.x, a.y, a.z, a.w};
#pragma unroll
      for (int kk = 0; kk < 4; ++kk) {
        acc[i][0] = fmaf(av[kk], b[kk].x, acc[i][0]);
        acc[i][1] = fmaf(av[kk], b[kk].y, acc[i][1]);
        acc[i][2] = fmaf(av[kk], b[kk].z, acc[i][2]);
        acc[i][3] = fmaf(av[kk], b[kk].w, acc[i][3]);
      }
    }
  }
#pragma unroll
  for (int i = 0; i < 4; ++i) {
    int r = r0 + rg * 4 + i;
    if (r < N_NODES) {
      float d = dinv[r];
      ushort4 p;
      p.x = f2bf(d * acc[i][0]);
      p.y = f2bf(d * acc[i][1]);
      p.z = f2bf(d * acc[i][2]);
      p.w = f2bf(d * acc[i][3]);
      reinterpret_cast<ushort4*>(G)[(size_t)r * 32 + (c0 >> 2) + cg] = p;
    }
  }
}

// ---------------- aggregation: wave per node, bf16 gather ----------------
__global__ __launch_bounds__(256) void k_agg(const uint32* __restrict__ g,
                                             const int* __restrict__ offs,
                                             const int* __restrict__ csr,
                                             const float* __restrict__ dinv,
                                             const float* __restrict__ bc,
                                             float* __restrict__ xo) {
  int w = threadIdx.x >> 6;
  int i = blockIdx.x * 4 + w;
  if (i >= N_NODES) return;
  int l = threadIdx.x & 63;

  uint32 u = g[(size_t)i * 64 + l];  // self-loop term
  float ax = bf_lo(u), ay = bf_hi(u);

  int e0 = offs[i], e1 = offs[i + 1];
  for (int base = e0; base < e1; base += 64) {
    int cnt = min(64, e1 - base);
    int myidx = (l < cnt) ? csr[base + l] : 0;
    int j = 0;
    for (; j + 4 <= cnt; j += 4) {
      int s0 = __shfl(myidx, j);
      int s1 = __shfl(myidx, j + 1);
      int s2 = __shfl(myidx, j + 2);
      int s3 = __shfl(myidx, j + 3);
      uint32 u0 = g[(size_t)s0 * 64 + l];
      uint32 u1 = g[(size_t)s1 * 64 + l];
      uint32 u2 = g[(size_t)s2 * 64 + l];
      uint32 u3 = g[(size_t)s3 * 64 + l];
      ax += bf_lo(u0); ay += bf_hi(u0);
      ax += bf_lo(u1); ay += bf_hi(u1);
      ax += bf_lo(u2); ay += bf_hi(u2);
      ax += bf_lo(u3); ay += bf_hi(u3);
    }
    for (; j < cnt; ++j) {
      int s = __shfl(myidx, j);
      uint32 uu = g[(size_t)s * 64 + l];
      ax += bf_lo(uu); ay += bf_hi(uu);
    }
  }
  float di = dinv[i];
  const float2* b2 = reinterpret_cast<const float2*>(bc);
  float2 bb = b2[l];
  float2 o;
  o.x = fmaxf(fmaf(di, ax, bb.x), 0.f);
  o.y = fmaxf(fmaf(di, ay, bb.y), 0.f);
  reinterpret_cast<float2*>(xo)[(size_t)i * 64 + l] = o;
}

// ---------------- pooling ----------------
__global__ void k_gbounds(const int* __restrict__ batch, int* __restrict__ gstart) {
  int g = threadIdx.x;
  if (g > NGRAPH) return;
  int lo = 0, hi = N_NODES;
  while (lo < hi) {
    int mid = (lo + hi) >> 1;
    if (batch[mid] < g) lo = mid + 1; else hi = mid;
  }
  gstart[g] = lo;
}

__global__ __launch_bounds__(256) void k_pool(const float* __restrict__ x,
                                              const int* __restrict__ gstart,
                                              float* __restrict__ pool) {
  int g = blockIdx.x, ch = blockIdx.y;
  int s = gstart[g], e = gstart[g + 1];
  long len = e - s;
  int cs = s + (int)(len * ch / 8);
  int ce = s + (int)(len * (ch + 1) / 8);
  int sub = threadIdx.x >> 6, l = threadIdx.x & 63;
  const float2* x2 = reinterpret_cast<const float2*>(x);
  float2 acc = make_float2(0.f, 0.f);
  for (int n = cs + sub; n < ce; n += 4) {
    float2 v = x2[(size_t)n * 64 + l];
    acc.x += v.x;
    acc.y += v.y;
  }
  atomicAdd(&pool[g * D + 2 * l], acc.x);
  atomicAdd(&pool[g * D + 2 * l + 1], acc.y);
}

// ---------------- MLP head ----------------
__global__ __launch_bounds__(128) void k_fc(const float* __restrict__ pool,
                                            const float* __restrict__ Wf,
                                            const float* __restrict__ bf,
                                            float* __restrict__ out) {
  __shared__ float row[D];
  int g = blockIdx.x, c = threadIdx.x;
  row[c] = pool[g * D + c];
  __syncthreads();
  for (int l = 0; l < 3; ++l) {
    const float* W = Wf + l * D * D;
    float s = bf[l * D + c];
    for (int k = 0; k < D; ++k) s = fmaf(row[k], W[k * D + c], s);
    s = fmaxf(s, 0.f);
    __syncthreads();
    row[c] = s;
    __syncthreads();
  }
  out[g * D + c] = row[c];
}

extern "C" void kernel_launch(void* const* d_in, const int* in_sizes, int n_in,
                              void* d_out, int out_size, void* d_ws, size_t ws_size,
                              hipStream_t stream) {
  const float* x   = (const float*)d_in[0];
  const int*   ei  = (const int*)d_in[1];
  const int* batch = (const int*)d_in[2];
  const float* Wc  = (const float*)d_in[3];
  const float* bc  = (const float*)d_in[4];
  const float* Wf  = (const float*)d_in[5];
  const float* bf  = (const float*)d_in[6];
  float* out = (float*)d_out;
  const int* src = ei;
  const int* dst = ei + N_EDGES;

  char* ws = (char*)d_ws;
  size_t o = 0;
  auto take = [&](size_t b) -> void* {
    void* p = ws + o;
    o = (o + b + 255) & ~(size_t)255;
    return p;
  };
  int*   deg    = (int*)  take(N_NODES * 4);
  float* dinv   = (float*)take(N_NODES * 4);
  int*   offs   = (int*)  take((N_NODES + 1) * 4);
  int*   bsum   = (int*)  take(256 * 4);
  int*   bbase  = (int*)  take(256 * 4);
  int*   cursor = (int*)  take(N_NODES * 4);
  int*   csr    = (int*)  take(N_EDGES * 4);
  int*   gstart = (int*)  take(64 * 4);
  ushort16* gbuf = (ushort16*)take((size_t)N_NODES * D * 2);
  float* xbuf   = (float*)take((size_t)N_NODES * D * 4);
  float* pool   = (float*)take(NGRAPH * D * 4);
  (void)ws_size; (void)in_sizes; (void)n_in; (void)out_size;

  hipMemsetAsync(deg, 0, N_NODES * 4, stream);
  hipMemsetAsync(cursor, 0, N_NODES * 4, stream);
  hipMemsetAsync(pool, 0, NGRAPH * D * 4, stream);

  const int NB = (N_NODES + 255) / 256;
  k_deg<<<(N_EDGES + 255) / 256, 256, 0, stream>>>(dst, deg);
  k_dinv<<<NB, 256, 0, stream>>>(deg, dinv);
  k_scan1<<<NB, 256, 0, stream>>>(deg, offs, bsum);
  k_scan2<<<1, 256, 0, stream>>>(bsum, bbase, NB);
  k_scan3<<<NB, 256, 0, stream>>>(offs, bbase);
  k_fill<<<(N_EDGES + 255) / 256, 256, 0, stream>>>(src, dst, offs, cursor, csr);

  const float* xin = x;
  for (int l = 0; l < 3; ++l) {
    k_gemm<<<dim3((N_NODES + 63) / 64, 2), 256, 0, stream>>>(xin, Wc + l * D * D, dinv, gbuf);
    k_agg<<<(N_NODES + 3) / 4, 256, 0, stream>>>((const uint32*)gbuf, offs, csr, dinv, bc + l * D, xbuf);
    xin = xbuf;
  }
  k_gbounds<<<1, 64, 0, stream>>>(batch, gstart);
  k_pool<<<dim3(NGRAPH, 8), 256, 0, stream>>>(xbuf, gstart, pool);
  k_fc<<<NGRAPH, 128, 0, stream>>>(pool, Wf, bf, out);
}

// Round 3
// 299.404 us; speedup vs baseline: 1.6612x; 1.1158x over previous
//
#include <hip/hip_runtime.h>

#define N_NODES 50000
#define N_EDGES 800000
#define D 128
#define NGRAPH 50

typedef unsigned int uint32;
typedef unsigned short ushort16;

__device__ inline float bf_lo(uint32 u) { union { uint32 u; float f; } c; c.u = u << 16; return c.f; }
__device__ inline float bf_hi(uint32 u) { union { uint32 u; float f; } c; c.u = u & 0xffff0000u; return c.f; }
__device__ inline ushort16 f2bf(float f) {  // RNE
  union { float f; uint32 u; } c; c.f = f;
  uint32 r = (c.u + 0x7fffu + ((c.u >> 16) & 1u)) >> 16;
  return (ushort16)r;
}

// ---------------- setup: degree+rank, norm, CSR ----------------
__global__ void k_deg(const int* __restrict__ dst, int* __restrict__ deg,
                      int* __restrict__ rank) {
  int e = blockIdx.x * 256 + threadIdx.x;
  if (e < N_EDGES) rank[e] = atomicAdd(&deg[dst[e]], 1);
}

__global__ void k_dinv(const int* __restrict__ deg, float* __restrict__ dinv) {
  int i = blockIdx.x * 256 + threadIdx.x;
  if (i < N_NODES) dinv[i] = rsqrtf((float)deg[i] + 1.0f);  // +1 self loop
}

__global__ void k_scan1(const int* __restrict__ deg, int* __restrict__ offs,
                        int* __restrict__ bsum) {
  __shared__ int s[256];
  int t = threadIdx.x;
  int i = blockIdx.x * 256 + t;
  int v = (i < N_NODES) ? deg[i] : 0;
  s[t] = v;
  __syncthreads();
  for (int off = 1; off < 256; off <<= 1) {
    int tmp = (t >= off) ? s[t - off] : 0;
    __syncthreads();
    s[t] += tmp;
    __syncthreads();
  }
  if (i < N_NODES) offs[i] = s[t] - v;
  if (t == 255) bsum[blockIdx.x] = s[t];
}

__global__ void k_scan2(const int* __restrict__ bsum, int* __restrict__ bbase, int nb) {
  __shared__ int s[256];
  int t = threadIdx.x;
  int v = (t < nb) ? bsum[t] : 0;
  s[t] = v;
  __syncthreads();
  for (int off = 1; off < 256; off <<= 1) {
    int tmp = (t >= off) ? s[t - off] : 0;
    __syncthreads();
    s[t] += tmp;
    __syncthreads();
  }
  bbase[t] = s[t] - v;
}

__global__ void k_scan3(int* __restrict__ offs, const int* __restrict__ bbase) {
  int i = blockIdx.x * 256 + threadIdx.x;
  if (i < N_NODES) offs[i] += bbase[blockIdx.x];
  if (i == 0) offs[N_NODES] = N_EDGES;
}

__global__ void k_fill(const int* __restrict__ src, const int* __restrict__ dst,
                       const int* __restrict__ offs, const int* __restrict__ rank,
                       ushort16* __restrict__ csr) {
  int e = blockIdx.x * 256 + threadIdx.x;
  if (e < N_EDGES) {
    int d = dst[e];
    csr[offs[d] + rank[e]] = (ushort16)src[e];
  }
}

// ---------------- GEMM: G = rowscale(A @ W, dinv), bf16 out ----------------
__global__ __launch_bounds__(256) void k_gemm(const float* __restrict__ A,
                                              const float* __restrict__ W,
                                              const float* __restrict__ dinv,
                                              ushort16* __restrict__ G) {
  __shared__ float As[64][132];
  __shared__ float Bs[128][64];
  int r0 = blockIdx.x * 64;
  int c0 = blockIdx.y * 64;
  int t = threadIdx.x;

  for (int i = t; i < 2048; i += 256) {
    int row = i >> 5, c4 = i & 31;
    int gr = r0 + row;
    float4 v = make_float4(0.f, 0.f, 0.f, 0.f);
    if (gr < N_NODES) v = reinterpret_cast<const float4*>(A)[gr * 32 + c4];
    *reinterpret_cast<float4*>(&As[row][c4 * 4]) = v;
  }
  for (int i = t; i < 2048; i += 256) {
    int row = i >> 4, c4 = i & 15;
    *reinterpret_cast<float4*>(&Bs[row][c4 * 4]) =
        reinterpret_cast<const float4*>(W)[row * 32 + (c0 >> 2) + c4];
  }
  __syncthreads();

  int cg = t & 15, rg = t >> 4;
  float acc[4][4] = {};
  for (int k = 0; k < 128; k += 4) {
    float4 b[4];
#pragma unroll
    for (int kk = 0; kk < 4; ++kk)
      b[kk] = *reinterpret_cast<const float4*>(&Bs[k + kk][cg * 4]);
#pragma unroll
    for (int i = 0; i < 4; ++i) {
      float4 a = *reinterpret_cast<const float4*>(&As[rg * 4 + i][k]);
      float av[4] = {a.x, a.y, a.z, a.w};
#pragma unroll
      for (int kk = 0; kk < 4; ++kk) {
        acc[i][0] = fmaf(av[kk], b[kk].x, acc[i][0]);
        acc[i][1] = fmaf(av[kk], b[kk].y, acc[i][1]);
        acc[i][2] = fmaf(av[kk], b[kk].z, acc[i][2]);
        acc[i][3] = fmaf(av[kk], b[kk].w, acc[i][3]);
      }
    }
  }
#pragma unroll
  for (int i = 0; i < 4; ++i) {
    int r = r0 + rg * 4 + i;
    if (r < N_NODES) {
      float d = dinv[r];
      ushort4 p;
      p.x = f2bf(d * acc[i][0]);
      p.y = f2bf(d * acc[i][1]);
      p.z = f2bf(d * acc[i][2]);
      p.w = f2bf(d * acc[i][3]);
      reinterpret_cast<ushort4*>(G)[(size_t)r * 32 + (c0 >> 2) + cg] = p;
    }
  }
}

// ---------------- aggregation: wave per node, bf16 gather ----------------
__global__ __launch_bounds__(256) void k_agg(const uint32* __restrict__ g,
                                             const int* __restrict__ offs,
                                             const ushort16* __restrict__ csr,
                                             const float* __restrict__ dinv,
                                             const float* __restrict__ bc,
                                             float* __restrict__ xo) {
  int w = threadIdx.x >> 6;
  int i = blockIdx.x * 4 + w;
  if (i >= N_NODES) return;
  int l = threadIdx.x & 63;

  uint32 u = g[(size_t)i * 64 + l];  // self-loop term
  float ax = bf_lo(u), ay = bf_hi(u);

  int e0 = offs[i], e1 = offs[i + 1];
  for (int base = e0; base < e1; base += 64) {
    int cnt = min(64, e1 - base);
    int myidx = (l < cnt) ? (int)csr[base + l] : 0;
    int j = 0;
    for (; j + 8 <= cnt; j += 8) {
      int s0 = __shfl(myidx, j);
      int s1 = __shfl(myidx, j + 1);
      int s2 = __shfl(myidx, j + 2);
      int s3 = __shfl(myidx, j + 3);
      int s4 = __shfl(myidx, j + 4);
      int s5 = __shfl(myidx, j + 5);
      int s6 = __shfl(myidx, j + 6);
      int s7 = __shfl(myidx, j + 7);
      uint32 u0 = g[(size_t)s0 * 64 + l];
      uint32 u1 = g[(size_t)s1 * 64 + l];
      uint32 u2 = g[(size_t)s2 * 64 + l];
      uint32 u3 = g[(size_t)s3 * 64 + l];
      uint32 u4 = g[(size_t)s4 * 64 + l];
      uint32 u5 = g[(size_t)s5 * 64 + l];
      uint32 u6 = g[(size_t)s6 * 64 + l];
      uint32 u7 = g[(size_t)s7 * 64 + l];
      ax += bf_lo(u0); ay += bf_hi(u0);
      ax += bf_lo(u1); ay += bf_hi(u1);
      ax += bf_lo(u2); ay += bf_hi(u2);
      ax += bf_lo(u3); ay += bf_hi(u3);
      ax += bf_lo(u4); ay += bf_hi(u4);
      ax += bf_lo(u5); ay += bf_hi(u5);
      ax += bf_lo(u6); ay += bf_hi(u6);
      ax += bf_lo(u7); ay += bf_hi(u7);
    }
    for (; j < cnt; ++j) {
      int s = __shfl(myidx, j);
      uint32 uu = g[(size_t)s * 64 + l];
      ax += bf_lo(uu); ay += bf_hi(uu);
    }
  }
  float di = dinv[i];
  const float2* b2 = reinterpret_cast<const float2*>(bc);
  float2 bb = b2[l];
  float2 o;
  o.x = fmaxf(fmaf(di, ax, bb.x), 0.f);
  o.y = fmaxf(fmaf(di, ay, bb.y), 0.f);
  reinterpret_cast<float2*>(xo)[(size_t)i * 64 + l] = o;
}

// ---------------- pooling ----------------
__global__ void k_gbounds(const int* __restrict__ batch, int* __restrict__ gstart) {
  int g = threadIdx.x;
  if (g > NGRAPH) return;
  int lo = 0, hi = N_NODES;
  while (lo < hi) {
    int mid = (lo + hi) >> 1;
    if (batch[mid] < g) lo = mid + 1; else hi = mid;
  }
  gstart[g] = lo;
}

__global__ __launch_bounds__(256) void k_pool(const float* __restrict__ x,
                                              const int* __restrict__ gstart,
                                              float* __restrict__ pool) {
  int g = blockIdx.x, ch = blockIdx.y;
  int s = gstart[g], e = gstart[g + 1];
  long len = e - s;
  int cs = s + (int)(len * ch / 8);
  int ce = s + (int)(len * (ch + 1) / 8);
  int sub = threadIdx.x >> 6, l = threadIdx.x & 63;
  const float2* x2 = reinterpret_cast<const float2*>(x);
  float2 acc = make_float2(0.f, 0.f);
  for (int n = cs + sub; n < ce; n += 4) {
    float2 v = x2[(size_t)n * 64 + l];
    acc.x += v.x;
    acc.y += v.y;
  }
  atomicAdd(&pool[g * D + 2 * l], acc.x);
  atomicAdd(&pool[g * D + 2 * l + 1], acc.y);
}

// ---------------- MLP head ----------------
__global__ __launch_bounds__(128) void k_fc(const float* __restrict__ pool,
                                            const float* __restrict__ Wf,
                                            const float* __restrict__ bf,
                                            float* __restrict__ out) {
  __shared__ float row[D];
  int g = blockIdx.x, c = threadIdx.x;
  row[c] = pool[g * D + c];
  __syncthreads();
  for (int l = 0; l < 3; ++l) {
    const float* W = Wf + l * D * D;
    float s = bf[l * D + c];
    for (int k = 0; k < D; ++k) s = fmaf(row[k], W[k * D + c], s);
    s = fmaxf(s, 0.f);
    __syncthreads();
    row[c] = s;
    __syncthreads();
  }
  out[g * D + c] = row[c];
}

extern "C" void kernel_launch(void* const* d_in, const int* in_sizes, int n_in,
                              void* d_out, int out_size, void* d_ws, size_t ws_size,
                              hipStream_t stream) {
  const float* x   = (const float*)d_in[0];
  const int*   ei  = (const int*)d_in[1];
  const int* batch = (const int*)d_in[2];
  const float* Wc  = (const float*)d_in[3];
  const float* bc  = (const float*)d_in[4];
  const float* Wf  = (const float*)d_in[5];
  const float* bf  = (const float*)d_in[6];
  float* out = (float*)d_out;
  const int* src = ei;
  const int* dst = ei + N_EDGES;

  char* ws = (char*)d_ws;
  size_t o = 0;
  auto take = [&](size_t b) -> void* {
    void* p = ws + o;
    o = (o + b + 255) & ~(size_t)255;
    return p;
  };
  int*   deg    = (int*)  take(N_NODES * 4);
  float* dinv   = (float*)take(N_NODES * 4);
  int*   offs   = (int*)  take((N_NODES + 1) * 4);
  int*   bsum   = (int*)  take(256 * 4);
  int*   bbase  = (int*)  take(256 * 4);
  int*   rank   = (int*)  take((size_t)N_EDGES * 4);
  ushort16* csr = (ushort16*)take((size_t)N_EDGES * 2);
  int*   gstart = (int*)  take(64 * 4);
  ushort16* gbuf = (ushort16*)take((size_t)N_NODES * D * 2);
  float* xbuf   = (float*)take((size_t)N_NODES * D * 4);
  float* pool   = (float*)take(NGRAPH * D * 4);
  (void)ws_size; (void)in_sizes; (void)n_in; (void)out_size;

  hipMemsetAsync(deg, 0, N_NODES * 4, stream);
  hipMemsetAsync(pool, 0, NGRAPH * D * 4, stream);

  const int NB = (N_NODES + 255) / 256;
  k_deg<<<(N_EDGES + 255) / 256, 256, 0, stream>>>(dst, deg, rank);
  k_dinv<<<NB, 256, 0, stream>>>(deg, dinv);
  k_scan1<<<NB, 256, 0, stream>>>(deg, offs, bsum);
  k_scan2<<<1, 256, 0, stream>>>(bsum, bbase, NB);
  k_scan3<<<NB, 256, 0, stream>>>(offs, bbase);
  k_fill<<<(N_EDGES + 255) / 256, 256, 0, stream>>>(src, dst, offs, rank, csr);

  const float* xin = x;
  for (int l = 0; l < 3; ++l) {
    k_gemm<<<dim3((N_NODES + 63) / 64, 2), 256, 0, stream>>>(xin, Wc + l * D * D, dinv, gbuf);
    k_agg<<<(N_NODES + 3) / 4, 256, 0, stream>>>((const uint32*)gbuf, offs, csr, dinv, bc + l * D, xbuf);
    xin = xbuf;
  }
  k_gbounds<<<1, 64, 0, stream>>>(batch, gstart);
  k_pool<<<dim3(NGRAPH, 8), 256, 0, stream>>>(xbuf, gstart, pool);
  k_fc<<<NGRAPH, 128, 0, stream>>>(pool, Wf, bf, out);
}

// Round 4
// 269.802 us; speedup vs baseline: 1.8434x; 1.1097x over previous
//
#include <hip/hip_runtime.h>

#define N_NODES 50000
#define N_EDGES 800000
#define D 128
#define NGRAPH 50

typedef unsigned int uint32;
typedef unsigned short ushort16;
typedef __attribute__((ext_vector_type(8))) short short8;
typedef __attribute__((ext_vector_type(4))) float f32x4;

__device__ inline float bf_lo(uint32 u) { union { uint32 u; float f; } c; c.u = u << 16; return c.f; }
__device__ inline float bf_hi(uint32 u) { union { uint32 u; float f; } c; c.u = u & 0xffff0000u; return c.f; }
__device__ inline ushort16 f2bf(float f) {  // RNE
  union { float f; uint32 u; } c; c.f = f;
  uint32 r = (c.u + 0x7fffu + ((c.u >> 16) & 1u)) >> 16;
  return (ushort16)r;
}

// ---------------- setup: degree+rank, norm, CSR ----------------
__global__ void k_deg(const int* __restrict__ dst, int* __restrict__ deg,
                      int* __restrict__ rank) {
  int e = blockIdx.x * 256 + threadIdx.x;
  if (e < N_EDGES) rank[e] = atomicAdd(&deg[dst[e]], 1);
}

__global__ void k_dinv(const int* __restrict__ deg, float* __restrict__ dinv) {
  int i = blockIdx.x * 256 + threadIdx.x;
  if (i < N_NODES) dinv[i] = rsqrtf((float)deg[i] + 1.0f);  // +1 self loop
}

__global__ void k_scan1(const int* __restrict__ deg, int* __restrict__ offs,
                        int* __restrict__ bsum) {
  __shared__ int s[256];
  int t = threadIdx.x;
  int i = blockIdx.x * 256 + t;
  int v = (i < N_NODES) ? deg[i] : 0;
  s[t] = v;
  __syncthreads();
  for (int off = 1; off < 256; off <<= 1) {
    int tmp = (t >= off) ? s[t - off] : 0;
    __syncthreads();
    s[t] += tmp;
    __syncthreads();
  }
  if (i < N_NODES) offs[i] = s[t] - v;
  if (t == 255) bsum[blockIdx.x] = s[t];
}

__global__ void k_scan2(const int* __restrict__ bsum, int* __restrict__ bbase, int nb) {
  __shared__ int s[256];
  int t = threadIdx.x;
  int v = (t < nb) ? bsum[t] : 0;
  s[t] = v;
  __syncthreads();
  for (int off = 1; off < 256; off <<= 1) {
    int tmp = (t >= off) ? s[t - off] : 0;
    __syncthreads();
    s[t] += tmp;
    __syncthreads();
  }
  bbase[t] = s[t] - v;
}

__global__ void k_scan3(int* __restrict__ offs, const int* __restrict__ bbase) {
  int i = blockIdx.x * 256 + threadIdx.x;
  if (i < N_NODES) offs[i] += bbase[blockIdx.x];
  if (i == 0) offs[N_NODES] = N_EDGES;
}

__global__ void k_fill(const int* __restrict__ src, const int* __restrict__ dst,
                       const int* __restrict__ offs, const int* __restrict__ rank,
                       ushort16* __restrict__ csr) {
  int e = blockIdx.x * 256 + threadIdx.x;
  if (e < N_EDGES) {
    int d = dst[e];
    csr[offs[d] + rank[e]] = (ushort16)src[e];
  }
}

// ---------------- casts ----------------
__global__ void k_cast(const float4* __restrict__ x, ushort4* __restrict__ xb) {
  int i = blockIdx.x * 256 + threadIdx.x;
  if (i < N_NODES * 32) {
    float4 v = x[i];
    ushort4 o;
    o.x = f2bf(v.x); o.y = f2bf(v.y); o.z = f2bf(v.z); o.w = f2bf(v.w);
    xb[i] = o;
  }
}

// WT[l][n][k] = Wc[l][k][n], bf16
__global__ void k_wt(const float* __restrict__ Wc, ushort16* __restrict__ WT) {
  int i = blockIdx.x * 256 + threadIdx.x;
  if (i < 3 * 128 * 128) {
    int layer = i >> 14, rem = i & 16383;
    int n = rem >> 7, k = rem & 127;
    WT[i] = f2bf(Wc[layer * 16384 + k * 128 + n]);
  }
}

// ---------------- GEMM (MFMA): G = rowscale(A @ W, dinv), bf16 in/out ----------------
// A: [N,128] bf16 row-major. WT: [128][128] bf16, WT[n][k]. 4 waves/block, 16 rows/wave.
__global__ __launch_bounds__(256) void k_gemm(const ushort16* __restrict__ A,
                                              const ushort16* __restrict__ WT,
                                              const float* __restrict__ dinv,
                                              ushort16* __restrict__ G) {
  __shared__ ushort16 so[4][16][136];  // 17408 B
  int t = threadIdx.x;
  int wave = t >> 6, l = t & 63;
  int cl = l & 15, kgrp = l >> 4;
  int rb = blockIdx.x * 64;
  int r0 = rb + wave * 16;
  int arow = r0 + cl;
  bool valid = arow < N_NODES;

  const short8* A8 = reinterpret_cast<const short8*>(A);
  const short8* B8 = reinterpret_cast<const short8*>(WT);

  f32x4 acc[8] = {};
#pragma unroll
  for (int k0 = 0; k0 < 4; ++k0) {
    short8 a = {};
    if (valid) a = A8[(size_t)arow * 16 + k0 * 4 + kgrp];
#pragma unroll
    for (int c = 0; c < 8; ++c) {
      short8 b = B8[(c * 16 + cl) * 16 + k0 * 4 + kgrp];
      acc[c] = __builtin_amdgcn_mfma_f32_16x16x32_bf16(a, b, acc[c], 0, 0, 0);
    }
  }

  // C/D layout: col = l&15, row = (l>>4)*4 + reg
  int rloc = kgrp * 4;
  float dj[4];
#pragma unroll
  for (int j = 0; j < 4; ++j) {
    int rr = r0 + rloc + j;
    dj[j] = (rr < N_NODES) ? dinv[rr] : 0.f;
  }
#pragma unroll
  for (int c = 0; c < 8; ++c) {
#pragma unroll
    for (int j = 0; j < 4; ++j) {
      so[wave][rloc + j][c * 16 + cl] = f2bf(dj[j] * acc[c][j]);
    }
  }
  // same-wave produce/consume; no cross-wave sharing -> no barrier needed
#pragma unroll
  for (int i = 0; i < 4; ++i) {
    int idx = i * 64 + l;
    int rr = idx >> 4, ch = idx & 15;
    int grow = r0 + rr;
    if (grow < N_NODES) {
      *reinterpret_cast<uint4*>(&(((ushort16*)G)[(size_t)grow * 128 + ch * 8])) =
          *reinterpret_cast<const uint4*>(&so[wave][rr][ch * 8]);
    }
  }
}

// ---------------- aggregation: wave per node, bf16 gather ----------------
template <int OUT_BF16>
__global__ __launch_bounds__(256) void k_agg(const uint32* __restrict__ g,
                                             const int* __restrict__ offs,
                                             const ushort16* __restrict__ csr,
                                             const float* __restrict__ dinv,
                                             const float* __restrict__ bc,
                                             void* __restrict__ xo) {
  int w = threadIdx.x >> 6;
  int i = blockIdx.x * 4 + w;
  if (i >= N_NODES) return;
  int l = threadIdx.x & 63;

  uint32 u = g[(size_t)i * 64 + l];  // self-loop term
  float ax = bf_lo(u), ay = bf_hi(u);

  int e0 = offs[i], e1 = offs[i + 1];
  for (int base = e0; base < e1; base += 64) {
    int cnt = min(64, e1 - base);
    int myidx = (l < cnt) ? (int)csr[base + l] : 0;
    int j = 0;
    for (; j + 8 <= cnt; j += 8) {
      int s0 = __shfl(myidx, j);
      int s1 = __shfl(myidx, j + 1);
      int s2 = __shfl(myidx, j + 2);
      int s3 = __shfl(myidx, j + 3);
      int s4 = __shfl(myidx, j + 4);
      int s5 = __shfl(myidx, j + 5);
      int s6 = __shfl(myidx, j + 6);
      int s7 = __shfl(myidx, j + 7);
      uint32 u0 = g[(size_t)s0 * 64 + l];
      uint32 u1 = g[(size_t)s1 * 64 + l];
      uint32 u2 = g[(size_t)s2 * 64 + l];
      uint32 u3 = g[(size_t)s3 * 64 + l];
      uint32 u4 = g[(size_t)s4 * 64 + l];
      uint32 u5 = g[(size_t)s5 * 64 + l];
      uint32 u6 = g[(size_t)s6 * 64 + l];
      uint32 u7 = g[(size_t)s7 * 64 + l];
      ax += bf_lo(u0); ay += bf_hi(u0);
      ax += bf_lo(u1); ay += bf_hi(u1);
      ax += bf_lo(u2); ay += bf_hi(u2);
      ax += bf_lo(u3); ay += bf_hi(u3);
      ax += bf_lo(u4); ay += bf_hi(u4);
      ax += bf_lo(u5); ay += bf_hi(u5);
      ax += bf_lo(u6); ay += bf_hi(u6);
      ax += bf_lo(u7); ay += bf_hi(u7);
    }
    for (; j < cnt; ++j) {
      int s = __shfl(myidx, j);
      uint32 uu = g[(size_t)s * 64 + l];
      ax += bf_lo(uu); ay += bf_hi(uu);
    }
  }
  float di = dinv[i];
  const float2* b2 = reinterpret_cast<const float2*>(bc);
  float2 bb = b2[l];
  float ox = fmaxf(fmaf(di, ax, bb.x), 0.f);
  float oy = fmaxf(fmaf(di, ay, bb.y), 0.f);
  if (OUT_BF16) {
    ushort2 o;
    o.x = f2bf(ox);
    o.y = f2bf(oy);
    reinterpret_cast<ushort2*>(xo)[(size_t)i * 64 + l] = o;
  } else {
    reinterpret_cast<float2*>(xo)[(size_t)i * 64 + l] = make_float2(ox, oy);
  }
}

// ---------------- pooling ----------------
__global__ void k_gbounds(const int* __restrict__ batch, int* __restrict__ gstart) {
  int g = threadIdx.x;
  if (g > NGRAPH) return;
  int lo = 0, hi = N_NODES;
  while (lo < hi) {
    int mid = (lo + hi) >> 1;
    if (batch[mid] < g) lo = mid + 1; else hi = mid;
  }
  gstart[g] = lo;
}

__global__ __launch_bounds__(256) void k_pool(const float* __restrict__ x,
                                              const int* __restrict__ gstart,
                                              float* __restrict__ pool) {
  int g = blockIdx.x, ch = blockIdx.y;
  int s = gstart[g], e = gstart[g + 1];
  long len = e - s;
  int cs = s + (int)(len * ch / 8);
  int ce = s + (int)(len * (ch + 1) / 8);
  int sub = threadIdx.x >> 6, l = threadIdx.x & 63;
  const float2* x2 = reinterpret_cast<const float2*>(x);
  float2 acc = make_float2(0.f, 0.f);
  for (int n = cs + sub; n < ce; n += 4) {
    float2 v = x2[(size_t)n * 64 + l];
    acc.x += v.x;
    acc.y += v.y;
  }
  atomicAdd(&pool[g * D + 2 * l], acc.x);
  atomicAdd(&pool[g * D + 2 * l + 1], acc.y);
}

// ---------------- MLP head ----------------
__global__ __launch_bounds__(128) void k_fc(const float* __restrict__ pool,
                                            const float* __restrict__ Wf,
                                            const float* __restrict__ bf,
                                            float* __restrict__ out) {
  __shared__ float row[D];
  int g = blockIdx.x, c = threadIdx.x;
  row[c] = pool[g * D + c];
  __syncthreads();
  for (int l = 0; l < 3; ++l) {
    const float* W = Wf + l * D * D;
    float s = bf[l * D + c];
    for (int k = 0; k < D; ++k) s = fmaf(row[k], W[k * D + c], s);
    s = fmaxf(s, 0.f);
    __syncthreads();
    row[c] = s;
    __syncthreads();
  }
  out[g * D + c] = row[c];
}

extern "C" void kernel_launch(void* const* d_in, const int* in_sizes, int n_in,
                              void* d_out, int out_size, void* d_ws, size_t ws_size,
                              hipStream_t stream) {
  const float* x   = (const float*)d_in[0];
  const int*   ei  = (const int*)d_in[1];
  const int* batch = (const int*)d_in[2];
  const float* Wc  = (const float*)d_in[3];
  const float* bc  = (const float*)d_in[4];
  const float* Wf  = (const float*)d_in[5];
  const float* bf  = (const float*)d_in[6];
  float* out = (float*)d_out;
  const int* src = ei;
  const int* dst = ei + N_EDGES;

  char* ws = (char*)d_ws;
  size_t o = 0;
  auto take = [&](size_t b) -> void* {
    void* p = ws + o;
    o = (o + b + 255) & ~(size_t)255;
    return p;
  };
  int*   deg    = (int*)  take(N_NODES * 4);
  float* dinv   = (float*)take(N_NODES * 4);
  int*   offs   = (int*)  take((N_NODES + 1) * 4);
  int*   bsum   = (int*)  take(256 * 4);
  int*   bbase  = (int*)  take(256 * 4);
  int*   rank   = (int*)  take((size_t)N_EDGES * 4);
  ushort16* csr = (ushort16*)take((size_t)N_EDGES * 2);
  int*   gstart = (int*)  take(64 * 4);
  ushort16* xb  = (ushort16*)take((size_t)N_NODES * D * 2);
  ushort16* WT  = (ushort16*)take((size_t)3 * D * D * 2);
  ushort16* gbuf = (ushort16*)take((size_t)N_NODES * D * 2);
  float* xbuf   = (float*)take((size_t)N_NODES * D * 4);
  float* pool   = (float*)take(NGRAPH * D * 4);
  (void)ws_size; (void)in_sizes; (void)n_in; (void)out_size;

  hipMemsetAsync(deg, 0, N_NODES * 4, stream);
  hipMemsetAsync(pool, 0, NGRAPH * D * 4, stream);

  const int NB = (N_NODES + 255) / 256;
  k_deg<<<(N_EDGES + 255) / 256, 256, 0, stream>>>(dst, deg, rank);
  k_dinv<<<NB, 256, 0, stream>>>(deg, dinv);
  k_scan1<<<NB, 256, 0, stream>>>(deg, offs, bsum);
  k_scan2<<<1, 256, 0, stream>>>(bsum, bbase, NB);
  k_scan3<<<NB, 256, 0, stream>>>(offs, bbase);
  k_fill<<<(N_EDGES + 255) / 256, 256, 0, stream>>>(src, dst, offs, rank, csr);
  k_cast<<<(N_NODES * 32 + 255) / 256, 256, 0, stream>>>((const float4*)x, (ushort4*)xb);
  k_wt<<<(3 * 128 * 128 + 255) / 256, 256, 0, stream>>>(Wc, WT);

  const int GB = (N_NODES + 63) / 64;  // 782
  // layer 0
  k_gemm<<<GB, 256, 0, stream>>>(xb, WT + 0 * D * D, dinv, gbuf);
  k_agg<1><<<(N_NODES + 3) / 4, 256, 0, stream>>>((const uint32*)gbuf, offs, csr, dinv, bc + 0 * D, xb);
  // layer 1
  k_gemm<<<GB, 256, 0, stream>>>(xb, WT + 1 * D * D, dinv, gbuf);
  k_agg<1><<<(N_NODES + 3) / 4, 256, 0, stream>>>((const uint32*)gbuf, offs, csr, dinv, bc + 1 * D, xb);
  // layer 2 (f32 out for pooling)
  k_gemm<<<GB, 256, 0, stream>>>(xb, WT + 2 * D * D, dinv, gbuf);
  k_agg<0><<<(N_NODES + 3) / 4, 256, 0, stream>>>((const uint32*)gbuf, offs, csr, dinv, bc + 2 * D, xbuf);

  k_gbounds<<<1, 64, 0, stream>>>(batch, gstart);
  k_pool<<<dim3(NGRAPH, 8), 256, 0, stream>>>(xbuf, gstart, pool);
  k_fc<<<NGRAPH, 128, 0, stream>>>(pool, Wf, bf, out);
}